// Round 5
// baseline (87.493 us; speedup 1.0000x reference)
//
#include <hip/hip_runtime.h>

// CostVolume: out[b,c,d,h,w] = left[b,c,h,w] * right[b,c,h,w-d] (w>=d else 0),
// clipped to +-1000. B=1, C=32, H=160, W=320, D=64 (D runtime from out_size).
// Output f32 = 419.4 MB -> streaming-write-bound; fill kernel demonstrates
// ~6.9 TB/s on this chip => ~63 us floor.
//
// Structure: block = (c, 4-row h-tile), 320 threads; thread owns fixed
// (h',w4) float4 and loops over d.
//  - left loaded once to registers (global, read exactly once)
//  - right 4 rows staged in LDS with 16-f4 zero pad per row => w<d reads give
//    exact 0 with no per-element masking
//  - shifted window read = 2 aligned ds_read_b128 at 16B lane stride
//    (conflict-free; R1 kernel's 4 scalar reads were 8-way bank conflicts)
//  - d grouped by residue into 4 unrolled loops (template<int C0>) => A/B
//    element select is compile-time register renaming
//  - per-d store = 5120B contiguous run (was 1280B), nontemporal

typedef float fx4 __attribute__((ext_vector_type(4)));

constexpr float CLAMPV = 1000.0f;
constexpr int C   = 32;
constexpr int H   = 160;
constexpr int W   = 320;
constexpr int W4  = 80;            // float4 per row
constexpr int TH  = 4;             // h rows per block
constexpr int BLOCK = TH * W4;     // 320 threads = 5 waves
constexpr int PAD = 16;            // f4 zero-pad per row (covers d<=63; D<=64)
constexpr int RS  = PAD + W4;      // padded row stride in f4 (96)

__device__ __forceinline__ fx4 clamp4(fx4 l, fx4 r) {
    fx4 o;
    o.x = fminf(fmaxf(l.x * r.x, -CLAMPV), CLAMPV);
    o.y = fminf(fmaxf(l.y * r.y, -CLAMPV), CLAMPV);
    o.z = fminf(fmaxf(l.z * r.z, -CLAMPV), CLAMPV);
    o.w = fminf(fmaxf(l.w * r.w, -CLAMPV), CLAMPV);
    return o;
}

// Window starts at float (4*w4 - d); O = start&3. Select elems O..O+3 of [A|B].
template<int O>
__device__ __forceinline__ fx4 shuf(const fx4 A, const fx4 B) {
    if constexpr (O == 0) {
        return A;
    } else if constexpr (O == 1) {
        fx4 r = {A.y, A.z, A.w, B.x}; return r;
    } else if constexpr (O == 2) {
        fx4 r = {A.z, A.w, B.x, B.y}; return r;
    } else {
        fx4 r = {A.w, B.x, B.y, B.z}; return r;
    }
}

// One d-group: d = C0, C0+4, C0+8, ...
template<int C0>
__device__ __forceinline__ void group(const fx4* __restrict__ Ab, const fx4 l,
                                      float* __restrict__ ob, int w4, int D,
                                      size_t DSTRIDE) {
    constexpr int O = (4 - (C0 & 3)) & 3;    // element offset within A
    const int kmax = (D - C0 + 3) >> 2;
    float* p = ob + (size_t)C0 * DSTRIDE;
    int qa = w4 - (C0 ? 1 : 0);
    for (int k = 0; k < kmax; ++k, --qa, p += 4 * DSTRIDE) {
        const fx4 A = Ab[qa];
        fx4 r;
        if constexpr (O == 0) {
            r = A;
        } else {
            const fx4 B = Ab[qa + 1];
            r = shuf<O>(A, B);
        }
        const fx4 o = clamp4(l, r);
        __builtin_nontemporal_store(o, reinterpret_cast<fx4*>(p));
    }
}

__global__ __launch_bounds__(BLOCK) void costvol_kernel(
    const float* __restrict__ left,
    const float* __restrict__ right,
    float* __restrict__ out,
    int D)
{
    const int blk = blockIdx.x;            // c*(H/TH) + htile
    const int c   = blk / (H / TH);        // compile-time divisors
    const int h0  = (blk - c * (H / TH)) * TH;

    __shared__ fx4 sR[TH * RS];            // 6 KB

    const int t = threadIdx.x;             // 0..319
    const size_t inbase = ((size_t)c * H + h0) * W;   // rows h0..h0+3 contiguous
    const fx4* lg = reinterpret_cast<const fx4*>(left  + inbase);
    const fx4* rg = reinterpret_cast<const fx4*>(right + inbase);

    // stage right tile (+ zero pads); left goes straight to registers
    if (t < TH * PAD) {
        const int row = t / PAD, col = t - row * PAD;
        fx4 z = {0.f, 0.f, 0.f, 0.f};
        sR[row * RS + col] = z;
    }
    {
        const int row = t / W4, col = t - row * W4;
        sR[row * RS + PAD + col] = rg[t];
    }
    const fx4 l = lg[t];
    __syncthreads();

    const int h_ = t / W4;
    const int w4 = t - h_ * W4;
    const fx4* Ab = sR + h_ * RS + PAD;    // Ab[q]: q may go negative into pad
    float* ob = out + ((size_t)c * D * H + h0) * W + 4 * (size_t)t;
    const size_t DSTRIDE = (size_t)H * W;  // floats per d slice

    group<0>(Ab, l, ob, w4, D, DSTRIDE);   // d = 0,4,8,...   O=0
    group<3>(Ab, l, ob, w4, D, DSTRIDE);   // d = 3,7,11,...  O=1
    group<2>(Ab, l, ob, w4, D, DSTRIDE);   // d = 2,6,10,...  O=2
    group<1>(Ab, l, ob, w4, D, DSTRIDE);   // d = 1,5,9,...   O=3
}

extern "C" void kernel_launch(void* const* d_in, const int* in_sizes, int n_in,
                              void* d_out, int out_size, void* d_ws, size_t ws_size,
                              hipStream_t stream) {
    const float* left  = (const float*)d_in[0];
    const float* right = (const float*)d_in[1];
    float* out = (float*)d_out;

    const int D = out_size / in_sizes[0];   // 64 with the fixed setup

    dim3 grid(C * (H / TH), 1, 1);          // 32 * 40 = 1280 blocks
    dim3 block(BLOCK, 1, 1);
    costvol_kernel<<<grid, block, 0, stream>>>(left, right, out, D);
}